// Round 5
// baseline (203.160 us; speedup 1.0000x reference)
//
#include <hip/hip_runtime.h>
#include <hip/hip_bf16.h>
#include <math.h>

typedef unsigned short u16;
typedef unsigned int u32;
typedef __attribute__((ext_vector_type(8))) short frag8;   // 8 x bf16 (4 VGPR)
typedef __attribute__((ext_vector_type(4))) float facc4;   // 16x16 MFMA accumulator
typedef __attribute__((ext_vector_type(16))) float facc16; // 32x32 MFMA accumulator
typedef __attribute__((ext_vector_type(2))) int v2i;
typedef __attribute__((ext_vector_type(4))) int i4;

typedef __attribute__((address_space(3))) void lds_void;
typedef const __attribute__((address_space(1))) void gbl_void;

__device__ __forceinline__ void gload16(const void* g, void* l) {
  __builtin_amdgcn_global_load_lds((gbl_void*)g, (lds_void*)l, 16, 0, 0);
}

__device__ __forceinline__ u16 f2bf(float f) {
  union { float f; unsigned u; } v; v.f = f;
  unsigned r = v.u + 0x7FFFu + ((v.u >> 16) & 1u);   // RNE
  return (u16)(r >> 16);
}

__device__ __forceinline__ u16 f2bf_hw(float f) {
  __hip_bfloat16 h = __float2bfloat16(f);
  return *(u16*)&h;
}

__device__ __forceinline__ float bf2f(u16 u) {
  return __int_as_float(((u32)u) << 16);
}

__device__ __forceinline__ u32 pack2bf(float a, float b) {
  return (u32)f2bf_hw(a) | ((u32)f2bf_hw(b) << 16);
}

__device__ __forceinline__ facc4 mfma16(frag8 a, frag8 b, facc4 c) {
  return __builtin_amdgcn_mfma_f32_16x16x32_bf16(a, b, c, 0, 0, 0);
}
__device__ __forceinline__ facc16 mfma32(frag8 a, frag8 b, facc16 c) {
  return __builtin_amdgcn_mfma_f32_32x32x16_bf16(a, b, c, 0, 0, 0);
}
__device__ __forceinline__ v2i pl32swap(int x, int y) {
  return __builtin_amdgcn_permlane32_swap(x, y, false, false);
}

// ---------------- fp32 -> bf16 convert ----------------
__global__ __launch_bounds__(256) void k_cvt(const float* __restrict__ in,
                                             u16* __restrict__ out, int n) {
  int i = (blockIdx.x * 256 + threadIdx.x) * 8;
  if (i >= n) return;
  float4 a = *(const float4*)(in + i);
  float4 b = *(const float4*)(in + i + 4);
  frag8 o;
  o[0] = (short)f2bf(a.x); o[1] = (short)f2bf(a.y);
  o[2] = (short)f2bf(a.z); o[3] = (short)f2bf(a.w);
  o[4] = (short)f2bf(b.x); o[5] = (short)f2bf(b.y);
  o[6] = (short)f2bf(b.z); o[7] = (short)f2bf(b.w);
  *(frag8*)(out + i) = o;
}

// ---------------- xa = x @ lora_a^T  (fp32, [4096][8]) ----------------
__global__ __launch_bounds__(256) void k_xa(const float* __restrict__ x,
                                            const float* __restrict__ la,
                                            float* __restrict__ xa) {
  const int row = blockIdx.x * 4 + (threadIdx.x >> 6);
  const int lane = threadIdx.x & 63;
  const float* xr = x + (size_t)row * 1024;
  float s[8];
#pragma unroll
  for (int j = 0; j < 8; ++j) s[j] = 0.f;
  for (int c = lane * 4; c < 1024; c += 256) {
    float4 xv = *(const float4*)(xr + c);
#pragma unroll
    for (int j = 0; j < 8; ++j) {
      float4 av = *(const float4*)(la + j * 1024 + c);
      s[j] += xv.x * av.x + xv.y * av.y + xv.z * av.z + xv.w * av.w;
    }
  }
#pragma unroll
  for (int j = 0; j < 8; ++j) {
#pragma unroll
    for (int m_ = 1; m_ < 64; m_ <<= 1) s[j] += __shfl_xor(s[j], m_);
  }
  if (lane == 0) {
#pragma unroll
    for (int j = 0; j < 8; ++j) xa[(size_t)row * 8 + j] = s[j];
  }
}

// ---------------- QKV GEMM: [4096,1024]x[3072,1024]^T + bias + LoRA ----------------
__global__ __launch_bounds__(256) void k_gemm_qkv(
    const u16* __restrict__ A, const u16* __restrict__ B,
    const float* __restrict__ bias, const float* __restrict__ xa,
    const float* __restrict__ lb,
    u16* __restrict__ qw, u16* __restrict__ kw, u16* __restrict__ vw) {
  __shared__ __align__(16) u16 As[128 * 64];
  __shared__ __align__(16) u16 Bs[128 * 64];
  const int mbase = blockIdx.y * 128;
  const int nbase = blockIdx.x * 128;
  const int t = threadIdx.x;
  const int lane = t & 63;
  const int w = t >> 6;
  const int wm = w >> 1, wn = w & 1;
  const facc4 vzero = {0.f, 0.f, 0.f, 0.f};
  facc4 acc[4][4];
#pragma unroll
  for (int i = 0; i < 4; ++i)
#pragma unroll
    for (int j = 0; j < 4; ++j) acc[i][j] = vzero;

  for (int kt = 0; kt < 16; ++kt) {
    __syncthreads();
#pragma unroll
    for (int i = 0; i < 4; ++i) {
      int c = i * 256 + t;
      int row = c >> 3, cs = c & 7;
      int scs = cs ^ (row & 7);                 // pre-swizzled global source
      gload16(A + (size_t)(mbase + row) * 1024 + kt * 64 + scs * 8,
              As + (size_t)(i * 256 + w * 64) * 8);
      gload16(B + (size_t)(nbase + row) * 1024 + kt * 64 + scs * 8,
              Bs + (size_t)(i * 256 + w * 64) * 8);
    }
    __syncthreads();
#pragma unroll
    for (int ks = 0; ks < 2; ++ks) {
      frag8 af[4], bfr[4];
#pragma unroll
      for (int mi = 0; mi < 4; ++mi) {
        int row = wm * 64 + mi * 16 + (lane & 15);
        int off = (ks * 64 + ((lane >> 4) << 4)) ^ ((row & 7) << 4);
        af[mi] = *(const frag8*)((const char*)As + row * 128 + off);
      }
#pragma unroll
      for (int ni = 0; ni < 4; ++ni) {
        int row = wn * 64 + ni * 16 + (lane & 15);
        int off = (ks * 64 + ((lane >> 4) << 4)) ^ ((row & 7) << 4);
        bfr[ni] = *(const frag8*)((const char*)Bs + row * 128 + off);
      }
#pragma unroll
      for (int mi = 0; mi < 4; ++mi)
#pragma unroll
        for (int ni = 0; ni < 4; ++ni)
          acc[mi][ni] = mfma16(af[mi], bfr[ni], acc[mi][ni]);
    }
  }
  // epilogue: bias + LoRA(fp32) + split/scale/scatter
  const int which = nbase >> 10;
  const int r0 = (lane >> 4) << 2;
  float bi_[4]; float4 lb0_[4], lb1_[4]; int hh[4], dd[4];
#pragma unroll
  for (int ni = 0; ni < 4; ++ni) {
    const int gc = nbase + wn * 64 + ni * 16 + (lane & 15);
    bi_[ni] = bias[gc];
    lb0_[ni] = *(const float4*)(lb + (size_t)gc * 8);
    lb1_[ni] = *(const float4*)(lb + (size_t)gc * 8 + 4);
    const int e = gc & 1023;
    hh[ni] = e >> 6; dd[ni] = e & 63;
  }
#pragma unroll
  for (int mi = 0; mi < 4; ++mi) {
#pragma unroll
    for (int r = 0; r < 4; ++r) {
      const int gr = mbase + wm * 64 + mi * 16 + r0 + r;
      const float4 xa0 = *(const float4*)(xa + (size_t)gr * 8);
      const float4 xa1 = *(const float4*)(xa + (size_t)gr * 8 + 4);
      const int bb = gr >> 11, s = gr & 2047;
      const size_t rbase = ((size_t)(bb * 16) * 2048 + (size_t)s) * 64;
#pragma unroll
      for (int ni = 0; ni < 4; ++ni) {
        float v = acc[mi][ni][r] + bi_[ni]
                + xa0.x * lb0_[ni].x + xa0.y * lb0_[ni].y + xa0.z * lb0_[ni].z + xa0.w * lb0_[ni].w
                + xa1.x * lb1_[ni].x + xa1.y * lb1_[ni].y + xa1.z * lb1_[ni].z + xa1.w * lb1_[ni].w;
        const size_t idx = rbase + (size_t)hh[ni] * (2048 * 64) + dd[ni];
        if (which == 0)      qw[idx] = f2bf(v * 0.125f);
        else if (which == 1) kw[idx] = f2bf(v);
        else                 vw[idx] = f2bf(v);
      }
    }
  }
}

// ---------------- V transpose: [B,H,S,D] -> [B,H,D,S] ----------------
__global__ __launch_bounds__(256) void k_vt(const u16* __restrict__ vp,
                                            u16* __restrict__ vt) {
  __shared__ u16 tile[64][72];
  const int s0 = blockIdx.x * 64;
  const size_t hoff = (size_t)blockIdx.y * (2048 * 64);
  const int t = threadIdx.x;
#pragma unroll
  for (int i = 0; i < 2; ++i) {
    int c = t + i * 256;
    int r = c >> 3, c8 = (c & 7) * 8;
    frag8 d = *(const frag8*)(vp + hoff + (size_t)(s0 + r) * 64 + c8);
#pragma unroll
    for (int j = 0; j < 8; ++j) tile[r][c8 + j] = (u16)d[j];
  }
  __syncthreads();
#pragma unroll
  for (int i = 0; i < 2; ++i) {
    int c = t + i * 256;
    int dd = c >> 3, scol = (c & 7) * 8;
    frag8 o;
#pragma unroll
    for (int j = 0; j < 8; ++j) o[j] = (short)tile[scol + j][dd];
    *(frag8*)(vt + hoff + (size_t)dd * 2048 + s0 + scol) = o;
  }
}

// ---------------- flash attention, split-KV (swapped QK^T, in-register softmax) ----
// q,k: [B,H,S,D] bf16 (q pre-scaled); vt: [B,H,D,S] bf16; mask [B,S,S] f32
// Each block does 16 KV tiles (half = blockIdx.z). Writes unnormalized partial O
// (bf16, [B,S,E] layout) + per-row (m,l) f32.
__global__ __launch_bounds__(256) void k_attn(
    const u16* __restrict__ qw, const u16* __restrict__ kw,
    const u16* __restrict__ vt, const float* __restrict__ mask,
    u16* __restrict__ p0, u16* __restrict__ p1,
    float2* __restrict__ ml0, float2* __restrict__ ml1) {
  __shared__ __align__(16) u16 Ks[2][64 * 64];   // [kv][d] rows 128B, XOR-swizzled
  __shared__ __align__(16) u16 Vs[2][64 * 64];   // [d][kv] rows 128B, XOR-swizzled
  const int qt = blockIdx.x, bh = blockIdx.y, half = blockIdx.z;
  const int b = bh >> 4, hd = bh & 15;
  u16* opart = half ? p1 : p0;
  float2* mlp = half ? ml1 : ml0;
  const int t = threadIdx.x, lane = t & 63, w = t >> 6;
  const int l31 = lane & 31, hh = lane >> 5;     // half of wave
  const int q = qt * 128 + w * 32 + l31;         // this lane's q-row (softmax state)
  const size_t hoff = (size_t)bh * (2048 * 64);
  const float L2E = 1.44269504088896341f;
  const int t0 = half * 16;                      // first KV tile of this half

  // Q as B-operand fragments: qf[dk] = Q[q][dk*16 + hh*8 + 0..7]
  frag8 qf[4];
  {
    const u16* qp = qw + hoff + (size_t)q * 64 + hh * 8;
#pragma unroll
    for (int dk = 0; dk < 4; ++dk) qf[dk] = *(const frag8*)(qp + dk * 16);
  }
  const float* mrow = mask + (size_t)(b * 2048 + q) * 2048;  // lane's mask row

  float mrun = -__builtin_inff(), lrun = 0.f;
  facc16 oacc[2];
#pragma unroll
  for (int nd = 0; nd < 2; ++nd)
#pragma unroll
    for (int rg = 0; rg < 16; ++rg) oacc[nd][rg] = 0.f;

  // stage KVBLK=64 tile: 4 gload16/thread (2 K + 2 V), pre-swizzled source
  auto STAGE = [&](int buf, int tile) {
    const int kv0 = tile * 64;
#pragma unroll
    for (int i = 0; i < 2; ++i) {
      int c = i * 256 + t;
      int r = c >> 3, cc = c & 7;
      int sc = cc ^ (r & 7);
      gload16(kw + hoff + (size_t)(kv0 + r) * 64 + sc * 8, (char*)&Ks[buf][0] + c * 16);
      gload16(vt + hoff + (size_t)r * 2048 + kv0 + sc * 8, (char*)&Vs[buf][0] + c * 16);
    }
  };

  STAGE(0, t0);

  for (int tt = 0; tt < 16; ++tt) {
    const int cur = tt & 1;
    const int kv0 = (t0 + tt) * 64;
    // mask loads for this tile (issued BEFORE the drain so they ride with compute)
    float4 mv[2][4];
#pragma unroll
    for (int kb = 0; kb < 2; ++kb)
#pragma unroll
      for (int rg2 = 0; rg2 < 4; ++rg2)
        mv[kb][rg2] = *(const float4*)(mrow + kv0 + kb * 32 + rg2 * 8 + hh * 4);
    // drain this tile's stage (4 oldest); keep the 8 mask loads in flight
    asm volatile("s_waitcnt vmcnt(8)" ::: "memory");
    __builtin_amdgcn_s_barrier();             // A: Ks/Vs[cur] visible to all waves
    if (tt + 1 < 16) STAGE(cur ^ 1, t0 + tt + 1);  // next tile rides through compute

    // S^T = K Q^T : lane holds S[k][q] for its q = l31, 32 k values in regs
    const char* ksb = (const char*)&Ks[cur][0];
    facc16 st[2];
    __builtin_amdgcn_s_setprio(1);
#pragma unroll
    for (int kb = 0; kb < 2; ++kb) {
      int row = kb * 32 + l31;
      int sw = (row & 7) << 4;
      const char* krow = ksb + row * 128;
      facc16 z;
#pragma unroll
      for (int rg = 0; rg < 16; ++rg) z[rg] = 0.f;
#pragma unroll
      for (int dk = 0; dk < 4; ++dk) {
        frag8 kf = *(const frag8*)(krow + ((dk * 32 + hh * 16) ^ sw));
        z = mfma32(kf, qf[dk], z);
      }
      st[kb] = z;
    }
    __builtin_amdgcn_s_setprio(0);
    // + mask: S^T reg rg -> k = (rg&3) + 8*(rg>>2) + 4*hh
#pragma unroll
    for (int kb = 0; kb < 2; ++kb)
#pragma unroll
      for (int rg2 = 0; rg2 < 4; ++rg2) {
        st[kb][rg2 * 4 + 0] += mv[kb][rg2].x;
        st[kb][rg2 * 4 + 1] += mv[kb][rg2].y;
        st[kb][rg2 * 4 + 2] += mv[kb][rg2].z;
        st[kb][rg2 * 4 + 3] += mv[kb][rg2].w;
      }
    // row max: in-register over 32, then combine halves with one permlane32_swap
    float tm = st[0][0];
#pragma unroll
    for (int kb = 0; kb < 2; ++kb)
#pragma unroll
      for (int rg = 0; rg < 16; ++rg) tm = fmaxf(tm, st[kb][rg]);
    {
      v2i r = pl32swap(__float_as_int(tm), __float_as_int(tm));
      tm = fmaxf(__int_as_float(r.x), __int_as_float(r.y));
    }
    // deferred rescale (cold path)
    if (__any(tm > mrun + 8.f)) {
      float nm = fmaxf(mrun, tm);
      float sc = exp2f((mrun - nm) * L2E);
      mrun = nm; lrun *= sc;
#pragma unroll
      for (int rg = 0; rg < 16; ++rg) {
        int q_r = (rg & 3) + 8 * (rg >> 2) + 4 * hh;
        float scq = __int_as_float(__builtin_amdgcn_ds_bpermute(q_r << 2, __float_as_int(sc)));
        oacc[0][rg] *= scq; oacc[1][rg] *= scq;
      }
    }
    // exp + row-sum + pack to bf16 pairs
    const float mL = mrun * L2E;
    float ps = 0.f;
    u32 u[2][4][2];
#pragma unroll
    for (int kb = 0; kb < 2; ++kb)
#pragma unroll
      for (int rg2 = 0; rg2 < 4; ++rg2) {
        float pp0 = exp2f(__builtin_fmaf(st[kb][rg2 * 4 + 0], L2E, -mL));
        float pp1 = exp2f(__builtin_fmaf(st[kb][rg2 * 4 + 1], L2E, -mL));
        float pp2 = exp2f(__builtin_fmaf(st[kb][rg2 * 4 + 2], L2E, -mL));
        float pp3 = exp2f(__builtin_fmaf(st[kb][rg2 * 4 + 3], L2E, -mL));
        ps += (pp0 + pp1) + (pp2 + pp3);
        u[kb][rg2][0] = pack2bf(pp0, pp1);
        u[kb][rg2][1] = pack2bf(pp2, pp3);
      }
    {
      v2i r = pl32swap(__float_as_int(ps), __float_as_int(ps));
      ps = __int_as_float(r.x) + __int_as_float(r.y);
    }
    lrun += ps;
    // PV: redistribute P via permlane32_swap into A-frags, mfma against Vs
    const char* vsb = (const char*)&Vs[cur][0];
    __builtin_amdgcn_s_setprio(1);
#pragma unroll
    for (int km = 0; km < 4; ++km) {
      const int kb = km >> 1, j = km & 1;
      v2i s0 = pl32swap(u[kb][2 * j][0], u[kb][2 * j + 1][0]);
      v2i s1 = pl32swap(u[kb][2 * j][1], u[kb][2 * j + 1][1]);
      i4 pw = { s0.x, s1.x, s0.y, s1.y };
      frag8 pf = *(frag8*)&pw;
#pragma unroll
      for (int nd = 0; nd < 2; ++nd) {
        int row = nd * 32 + l31;
        frag8 vf = *(const frag8*)(vsb + row * 128 +
                                   ((km * 32 + hh * 16) ^ ((row & 7) << 4)));
        oacc[nd] = mfma32(pf, vf, oacc[nd]);
      }
    }
    __builtin_amdgcn_s_setprio(0);
    asm volatile("s_waitcnt lgkmcnt(0)" ::: "memory");
    __builtin_amdgcn_s_barrier();             // B: all waves done reading buf[cur]
  }
  // epilogue: unnormalized partial O + (m,l); no normalization here
  if (hh == 0)
    mlp[(size_t)bh * 2048 + q] = make_float2(mrun, lrun);
#pragma unroll
  for (int rg = 0; rg < 16; ++rg) {
    int q_r = (rg & 3) + 8 * (rg >> 2) + 4 * hh;
    int gq = qt * 128 + w * 32 + q_r;
    size_t rowoff = (size_t)(b * 2048 + gq) * 1024 + hd * 64;
#pragma unroll
    for (int nd = 0; nd < 2; ++nd)
      opart[rowoff + nd * 32 + l31] = f2bf_hw(oacc[nd][rg]);
  }
}

// ---------------- split-KV reduce: combine 2 partials -> a_ws bf16 ----------------
__global__ __launch_bounds__(256) void k_red(
    const u16* __restrict__ p0, const u16* __restrict__ p1,
    const float2* __restrict__ ml0, const float2* __restrict__ ml1,
    u16* __restrict__ out) {
  const float L2E = 1.44269504088896341f;
  int idx = blockIdx.x * 256 + threadIdx.x;       // 524288 = 4096*1024/8
  int row = idx >> 7;                             // b*2048 + s
  int c8 = (idx & 127) * 8;
  int b = row >> 11, s = row & 2047;
  int h = c8 >> 6;
  int bhs = (b * 16 + h) * 2048 + s;
  float2 a = ml0[bhs], c = ml1[bhs];
  float m = fmaxf(a.x, c.x);
  float w0 = exp2f((a.x - m) * L2E);
  float w1 = exp2f((c.x - m) * L2E);
  float inv = 1.0f / (a.y * w0 + c.y * w1);
  float s0 = w0 * inv, s1 = w1 * inv;
  frag8 v0 = *(const frag8*)(p0 + (size_t)row * 1024 + c8);
  frag8 v1 = *(const frag8*)(p1 + (size_t)row * 1024 + c8);
  frag8 o;
#pragma unroll
  for (int j = 0; j < 8; ++j)
    o[j] = (short)f2bf_hw(bf2f((u16)v0[j]) * s0 + bf2f((u16)v1[j]) * s1);
  *(frag8*)(out + (size_t)row * 1024 + c8) = o;
}

// ---------------- out proj GEMM: [4096,1024]x[1024,1024]^T + bias -> fp32 ----------------
__global__ __launch_bounds__(256) void k_gemm_out(
    const u16* __restrict__ A, const u16* __restrict__ B,
    const float* __restrict__ bias, float* __restrict__ out) {
  __shared__ __align__(16) u16 As[128 * 64];
  __shared__ __align__(16) u16 Bs[128 * 64];
  const int mbase = blockIdx.y * 128;
  const int nbase = blockIdx.x * 128;
  const int t = threadIdx.x;
  const int lane = t & 63;
  const int w = t >> 6;
  const int wm = w >> 1, wn = w & 1;
  const facc4 vzero = {0.f, 0.f, 0.f, 0.f};
  facc4 acc[4][4];
#pragma unroll
  for (int i = 0; i < 4; ++i)
#pragma unroll
    for (int j = 0; j < 4; ++j) acc[i][j] = vzero;

  for (int kt = 0; kt < 16; ++kt) {
    __syncthreads();
#pragma unroll
    for (int i = 0; i < 4; ++i) {
      int c = i * 256 + t;
      int row = c >> 3, cs = c & 7;
      int scs = cs ^ (row & 7);
      gload16(A + (size_t)(mbase + row) * 1024 + kt * 64 + scs * 8,
              As + (size_t)(i * 256 + w * 64) * 8);
      gload16(B + (size_t)(nbase + row) * 1024 + kt * 64 + scs * 8,
              Bs + (size_t)(i * 256 + w * 64) * 8);
    }
    __syncthreads();
#pragma unroll
    for (int ks = 0; ks < 2; ++ks) {
      frag8 af[4], bfr[4];
#pragma unroll
      for (int mi = 0; mi < 4; ++mi) {
        int row = wm * 64 + mi * 16 + (lane & 15);
        int off = (ks * 64 + ((lane >> 4) << 4)) ^ ((row & 7) << 4);
        af[mi] = *(const frag8*)((const char*)As + row * 128 + off);
      }
#pragma unroll
      for (int ni = 0; ni < 4; ++ni) {
        int row = wn * 64 + ni * 16 + (lane & 15);
        int off = (ks * 64 + ((lane >> 4) << 4)) ^ ((row & 7) << 4);
        bfr[ni] = *(const frag8*)((const char*)Bs + row * 128 + off);
      }
#pragma unroll
      for (int mi = 0; mi < 4; ++mi)
#pragma unroll
        for (int ni = 0; ni < 4; ++ni)
          acc[mi][ni] = mfma16(af[mi], bfr[ni], acc[mi][ni]);
    }
  }
  const int r0 = (lane >> 4) << 2;
#pragma unroll
  for (int ni = 0; ni < 4; ++ni) {
    const int gc = nbase + wn * 64 + ni * 16 + (lane & 15);
    const float bi = bias[gc];
#pragma unroll
    for (int mi = 0; mi < 4; ++mi)
#pragma unroll
      for (int r = 0; r < 4; ++r) {
        const int gr = mbase + wm * 64 + mi * 16 + r0 + r;
        out[(size_t)gr * 1024 + gc] = acc[mi][ni][r] + bi;
      }
  }
}

extern "C" void kernel_launch(void* const* d_in, const int* in_sizes, int n_in,
                              void* d_out, int out_size, void* d_ws, size_t ws_size,
                              hipStream_t stream) {
  const float* x    = (const float*)d_in[0];
  const float* mask = (const float*)d_in[1];
  const float* wi   = (const float*)d_in[2];
  const float* bi   = (const float*)d_in[3];
  const float* wo   = (const float*)d_in[4];
  const float* bo   = (const float*)d_in[5];
  const float* la   = (const float*)d_in[6];
  const float* lb   = (const float*)d_in[7];
  float* out = (float*)d_out;

  char* ws = (char*)d_ws;
  u16* x_bf  = (u16*)ws;              ws += (size_t)4096 * 1024 * 2;   // reused: O partial 0
  u16* w_bf  = (u16*)ws;              ws += (size_t)3072 * 1024 * 2;
  u16* wo_bf = (u16*)ws;              ws += (size_t)1024 * 1024 * 2;
  u16* q_ws  = (u16*)ws;              ws += (size_t)4096 * 1024 * 2;
  u16* k_ws  = (u16*)ws;              ws += (size_t)4096 * 1024 * 2;
  u16* v_pre = (u16*)ws;              ws += (size_t)4096 * 1024 * 2;   // reused: O partial 1
  u16* v_t   = (u16*)ws;              ws += (size_t)4096 * 1024 * 2;
  u16* a_ws  = (u16*)ws;              ws += (size_t)4096 * 1024 * 2;
  float* xa  = (float*)ws;            ws += (size_t)4096 * 8 * 4;
  float2* ml0 = (float2*)ws;          ws += (size_t)32 * 2048 * 8;
  float2* ml1 = (float2*)ws;          ws += (size_t)32 * 2048 * 8;

  u16* o_p0 = x_bf;    // dead after k_gemm_qkv
  u16* o_p1 = v_pre;   // dead after k_vt

  k_cvt<<<dim3(2048), dim3(256), 0, stream>>>(x, x_bf, 4096 * 1024);
  k_cvt<<<dim3(1536), dim3(256), 0, stream>>>(wi, w_bf, 3072 * 1024);
  k_cvt<<<dim3(512),  dim3(256), 0, stream>>>(wo, wo_bf, 1024 * 1024);
  k_xa<<<dim3(1024), dim3(256), 0, stream>>>(x, la, xa);
  k_gemm_qkv<<<dim3(24, 32), dim3(256), 0, stream>>>(x_bf, w_bf, bi, xa, lb,
                                                     q_ws, k_ws, v_pre);
  k_vt<<<dim3(32, 32), dim3(256), 0, stream>>>(v_pre, v_t);
  k_attn<<<dim3(16, 32, 2), dim3(256), 0, stream>>>(q_ws, k_ws, v_t, mask,
                                                    o_p0, o_p1, ml0, ml1);
  k_red<<<dim3(2048), dim3(256), 0, stream>>>(o_p0, o_p1, ml0, ml1, a_ws);
  k_gemm_out<<<dim3(8, 32), dim3(256), 0, stream>>>(a_ws, wo_bf, bo, out);
}

// Round 6
// 186.860 us; speedup vs baseline: 1.0872x; 1.0872x over previous
//
#include <hip/hip_runtime.h>
#include <hip/hip_bf16.h>
#include <math.h>

typedef unsigned short u16;
typedef unsigned int u32;
typedef __attribute__((ext_vector_type(8))) short frag8;   // 8 x bf16 (4 VGPR)
typedef __attribute__((ext_vector_type(4))) float facc4;   // 16x16 MFMA accumulator
typedef __attribute__((ext_vector_type(16))) float facc16; // 32x32 MFMA accumulator
typedef __attribute__((ext_vector_type(2))) int v2i;
typedef __attribute__((ext_vector_type(4))) int i4;

typedef __attribute__((address_space(3))) void lds_void;
typedef const __attribute__((address_space(1))) void gbl_void;

__device__ __forceinline__ void gload16(const void* g, void* l) {
  __builtin_amdgcn_global_load_lds((gbl_void*)g, (lds_void*)l, 16, 0, 0);
}

__device__ __forceinline__ u16 f2bf(float f) {
  union { float f; unsigned u; } v; v.f = f;
  unsigned r = v.u + 0x7FFFu + ((v.u >> 16) & 1u);   // RNE
  return (u16)(r >> 16);
}

__device__ __forceinline__ u16 f2bf_hw(float f) {
  __hip_bfloat16 h = __float2bfloat16(f);
  return *(u16*)&h;
}

__device__ __forceinline__ facc4 mfma16(frag8 a, frag8 b, facc4 c) {
  return __builtin_amdgcn_mfma_f32_16x16x32_bf16(a, b, c, 0, 0, 0);
}
__device__ __forceinline__ facc16 mfma32(frag8 a, frag8 b, facc16 c) {
  return __builtin_amdgcn_mfma_f32_32x32x16_bf16(a, b, c, 0, 0, 0);
}
__device__ __forceinline__ v2i pl32swap(int x, int y) {
  return __builtin_amdgcn_permlane32_swap(x, y, false, false);
}
__device__ __forceinline__ float vmax3(float a, float b, float c) {
  float d;
  asm("v_max3_f32 %0, %1, %2, %3" : "=v"(d) : "v"(a), "v"(b), "v"(c));
  return d;
}
__device__ __forceinline__ u32 cvtpk(float lo, float hi) {   // lo->bits[15:0], hi->bits[31:16]
  u32 r;
  asm("v_cvt_pk_bf16_f32 %0, %1, %2" : "=v"(r) : "v"(lo), "v"(hi));
  return r;
}

// ---------------- fp32 -> bf16 convert ----------------
__global__ __launch_bounds__(256) void k_cvt(const float* __restrict__ in,
                                             u16* __restrict__ out, int n) {
  int i = (blockIdx.x * 256 + threadIdx.x) * 8;
  if (i >= n) return;
  float4 a = *(const float4*)(in + i);
  float4 b = *(const float4*)(in + i + 4);
  frag8 o;
  o[0] = (short)f2bf(a.x); o[1] = (short)f2bf(a.y);
  o[2] = (short)f2bf(a.z); o[3] = (short)f2bf(a.w);
  o[4] = (short)f2bf(b.x); o[5] = (short)f2bf(b.y);
  o[6] = (short)f2bf(b.z); o[7] = (short)f2bf(b.w);
  *(frag8*)(out + i) = o;
}

// ---------------- xa = x @ lora_a^T  (fp32, [4096][8]) ----------------
__global__ __launch_bounds__(256) void k_xa(const float* __restrict__ x,
                                            const float* __restrict__ la,
                                            float* __restrict__ xa) {
  const int row = blockIdx.x * 4 + (threadIdx.x >> 6);
  const int lane = threadIdx.x & 63;
  const float* xr = x + (size_t)row * 1024;
  float s[8];
#pragma unroll
  for (int j = 0; j < 8; ++j) s[j] = 0.f;
  for (int c = lane * 4; c < 1024; c += 256) {
    float4 xv = *(const float4*)(xr + c);
#pragma unroll
    for (int j = 0; j < 8; ++j) {
      float4 av = *(const float4*)(la + j * 1024 + c);
      s[j] += xv.x * av.x + xv.y * av.y + xv.z * av.z + xv.w * av.w;
    }
  }
#pragma unroll
  for (int j = 0; j < 8; ++j) {
#pragma unroll
    for (int m_ = 1; m_ < 64; m_ <<= 1) s[j] += __shfl_xor(s[j], m_);
  }
  if (lane == 0) {
#pragma unroll
    for (int j = 0; j < 8; ++j) xa[(size_t)row * 8 + j] = s[j];
  }
}

// ---------------- QKV GEMM: [4096,1024]x[3072,1024]^T + bias + LoRA ----------------
__global__ __launch_bounds__(256) void k_gemm_qkv(
    const u16* __restrict__ A, const u16* __restrict__ B,
    const float* __restrict__ bias, const float* __restrict__ xa,
    const float* __restrict__ lb,
    u16* __restrict__ qw, u16* __restrict__ kw, u16* __restrict__ vw) {
  __shared__ __align__(16) u16 As[128 * 64];
  __shared__ __align__(16) u16 Bs[128 * 64];
  const int mbase = blockIdx.y * 128;
  const int nbase = blockIdx.x * 128;
  const int t = threadIdx.x;
  const int lane = t & 63;
  const int w = t >> 6;
  const int wm = w >> 1, wn = w & 1;
  const facc4 vzero = {0.f, 0.f, 0.f, 0.f};
  facc4 acc[4][4];
#pragma unroll
  for (int i = 0; i < 4; ++i)
#pragma unroll
    for (int j = 0; j < 4; ++j) acc[i][j] = vzero;

  for (int kt = 0; kt < 16; ++kt) {
    __syncthreads();
#pragma unroll
    for (int i = 0; i < 4; ++i) {
      int c = i * 256 + t;
      int row = c >> 3, cs = c & 7;
      int scs = cs ^ (row & 7);                 // pre-swizzled global source
      gload16(A + (size_t)(mbase + row) * 1024 + kt * 64 + scs * 8,
              As + (size_t)(i * 256 + w * 64) * 8);
      gload16(B + (size_t)(nbase + row) * 1024 + kt * 64 + scs * 8,
              Bs + (size_t)(i * 256 + w * 64) * 8);
    }
    __syncthreads();
#pragma unroll
    for (int ks = 0; ks < 2; ++ks) {
      frag8 af[4], bfr[4];
#pragma unroll
      for (int mi = 0; mi < 4; ++mi) {
        int row = wm * 64 + mi * 16 + (lane & 15);
        int off = (ks * 64 + ((lane >> 4) << 4)) ^ ((row & 7) << 4);
        af[mi] = *(const frag8*)((const char*)As + row * 128 + off);
      }
#pragma unroll
      for (int ni = 0; ni < 4; ++ni) {
        int row = wn * 64 + ni * 16 + (lane & 15);
        int off = (ks * 64 + ((lane >> 4) << 4)) ^ ((row & 7) << 4);
        bfr[ni] = *(const frag8*)((const char*)Bs + row * 128 + off);
      }
#pragma unroll
      for (int mi = 0; mi < 4; ++mi)
#pragma unroll
        for (int ni = 0; ni < 4; ++ni)
          acc[mi][ni] = mfma16(af[mi], bfr[ni], acc[mi][ni]);
    }
  }
  // epilogue: bias + LoRA(fp32) + split/scale/scatter
  const int which = nbase >> 10;
  const int r0 = (lane >> 4) << 2;
  float bi_[4]; float4 lb0_[4], lb1_[4]; int hh[4], dd[4];
#pragma unroll
  for (int ni = 0; ni < 4; ++ni) {
    const int gc = nbase + wn * 64 + ni * 16 + (lane & 15);
    bi_[ni] = bias[gc];
    lb0_[ni] = *(const float4*)(lb + (size_t)gc * 8);
    lb1_[ni] = *(const float4*)(lb + (size_t)gc * 8 + 4);
    const int e = gc & 1023;
    hh[ni] = e >> 6; dd[ni] = e & 63;
  }
#pragma unroll
  for (int mi = 0; mi < 4; ++mi) {
#pragma unroll
    for (int r = 0; r < 4; ++r) {
      const int gr = mbase + wm * 64 + mi * 16 + r0 + r;
      const float4 xa0 = *(const float4*)(xa + (size_t)gr * 8);
      const float4 xa1 = *(const float4*)(xa + (size_t)gr * 8 + 4);
      const int bb = gr >> 11, s = gr & 2047;
      const size_t rbase = ((size_t)(bb * 16) * 2048 + (size_t)s) * 64;
#pragma unroll
      for (int ni = 0; ni < 4; ++ni) {
        float v = acc[mi][ni][r] + bi_[ni]
                + xa0.x * lb0_[ni].x + xa0.y * lb0_[ni].y + xa0.z * lb0_[ni].z + xa0.w * lb0_[ni].w
                + xa1.x * lb1_[ni].x + xa1.y * lb1_[ni].y + xa1.z * lb1_[ni].z + xa1.w * lb1_[ni].w;
        const size_t idx = rbase + (size_t)hh[ni] * (2048 * 64) + dd[ni];
        if (which == 0)      qw[idx] = f2bf(v * 0.125f);
        else if (which == 1) kw[idx] = f2bf(v);
        else                 vw[idx] = f2bf(v);
      }
    }
  }
}

// ---------------- V transpose: [B,H,S,D] -> [B,H,D,S] ----------------
__global__ __launch_bounds__(256) void k_vt(const u16* __restrict__ vp,
                                            u16* __restrict__ vt) {
  __shared__ u16 tile[64][72];
  const int s0 = blockIdx.x * 64;
  const size_t hoff = (size_t)blockIdx.y * (2048 * 64);
  const int t = threadIdx.x;
#pragma unroll
  for (int i = 0; i < 2; ++i) {
    int c = t + i * 256;
    int r = c >> 3, c8 = (c & 7) * 8;
    frag8 d = *(const frag8*)(vp + hoff + (size_t)(s0 + r) * 64 + c8);
#pragma unroll
    for (int j = 0; j < 8; ++j) tile[r][c8 + j] = (u16)d[j];
  }
  __syncthreads();
#pragma unroll
  for (int i = 0; i < 2; ++i) {
    int c = t + i * 256;
    int dd = c >> 3, scol = (c & 7) * 8;
    frag8 o;
#pragma unroll
    for (int j = 0; j < 8; ++j) o[j] = (short)tile[scol + j][dd];
    *(frag8*)(vt + hoff + (size_t)dd * 2048 + s0 + scol) = o;
  }
}

// ---------------- flash attention (swapped QK^T, in-register softmax) ----------------
// q,k: [B,H,S,D] bf16 (q pre-scaled); vt: [B,H,D,S] bf16; mask [B,S,S] f32
// out: [B,S,H*D] bf16. 4 waves x 32 q-rows = QBLK 128; KVBLK 64; 32x32x16 MFMA.
// Mask enters as MFMA C-in; LDS offsets hoisted; max3 reduce; cvt_pk packing.
__global__ __launch_bounds__(256) void k_attn(
    const u16* __restrict__ qw, const u16* __restrict__ kw,
    const u16* __restrict__ vt, const float* __restrict__ mask,
    u16* __restrict__ ao_out) {
  __shared__ __align__(16) u16 Ks[2][64 * 64];   // [kv][d] rows 128B, XOR-swizzled
  __shared__ __align__(16) u16 Vs[2][64 * 64];   // [d][kv] rows 128B, XOR-swizzled
  const int qt = blockIdx.x, bh = blockIdx.y;    // qt fast: mask sharers same XCD
  const int b = bh >> 4, hd = bh & 15;
  const int t = threadIdx.x, lane = t & 63, w = t >> 6;
  const int l31 = lane & 31, hh = lane >> 5;
  const int q = qt * 128 + w * 32 + l31;
  const size_t hoff = (size_t)bh * (2048 * 64);
  const float L2E = 1.44269504088896341f;

  frag8 qf[4];
  {
    const u16* qp = qw + hoff + (size_t)q * 64 + hh * 8;
#pragma unroll
    for (int dk = 0; dk < 4; ++dk) qf[dk] = *(const frag8*)(qp + dk * 16);
  }
  const float* mrow = mask + (size_t)(b * 2048 + q) * 2048;

  // hoisted LDS byte offsets (loop-invariant)
  int koff[8], voff[8];
#pragma unroll
  for (int kb = 0; kb < 2; ++kb) {
    int row = kb * 32 + l31, sw = (row & 7) << 4;
#pragma unroll
    for (int dk = 0; dk < 4; ++dk)
      koff[kb * 4 + dk] = row * 128 + ((dk * 32 + hh * 16) ^ sw);
  }
#pragma unroll
  for (int km = 0; km < 4; ++km)
#pragma unroll
    for (int nd = 0; nd < 2; ++nd) {
      int row = nd * 32 + l31, sw = (row & 7) << 4;
      voff[km * 2 + nd] = row * 128 + ((km * 32 + hh * 16) ^ sw);
    }

  float mrun = -__builtin_inff(), lrun = 0.f;
  facc16 oacc[2];
#pragma unroll
  for (int nd = 0; nd < 2; ++nd)
#pragma unroll
    for (int rg = 0; rg < 16; ++rg) oacc[nd][rg] = 0.f;

  auto STAGE = [&](int buf, int tile) {
    const int kv0 = tile * 64;
#pragma unroll
    for (int i = 0; i < 2; ++i) {
      int c = i * 256 + t;
      int r = c >> 3, cc = c & 7;
      int sc = cc ^ (r & 7);
      gload16(kw + hoff + (size_t)(kv0 + r) * 64 + sc * 8, (char*)&Ks[buf][0] + c * 16);
      gload16(vt + hoff + (size_t)r * 2048 + kv0 + sc * 8, (char*)&Vs[buf][0] + c * 16);
    }
  };

  STAGE(0, 0);

  typedef union { facc16 v; float4 f[4]; } ZU;

  for (int tt = 0; tt < 32; ++tt) {
    const int cur = tt & 1;
    const int kv0 = tt * 64;
    // mask loads straight into the accumulator union (MFMA C-in) — issued
    // BEFORE the drain so they overlap the barrier + QK^T
    ZU z[2];
    const float* mp = mrow + kv0 + hh * 4;
#pragma unroll
    for (int kb = 0; kb < 2; ++kb)
#pragma unroll
      for (int rg2 = 0; rg2 < 4; ++rg2)
        z[kb].f[rg2] = *(const float4*)(mp + kb * 32 + rg2 * 8);
    // drain this tile's stage (4 oldest); keep the 8 mask loads in flight
    asm volatile("s_waitcnt vmcnt(8)" ::: "memory");
    __builtin_amdgcn_s_barrier();             // A: Ks/Vs[cur] visible to all waves
    if (tt + 1 < 32) STAGE(cur ^ 1, tt + 1);  // next tile rides through compute

    // S^T = K Q^T + mask : lane holds S[k][q] for its q = l31
    const char* ksb = (const char*)&Ks[0][0] + cur * 8192;
    __builtin_amdgcn_s_setprio(1);
#pragma unroll
    for (int kb = 0; kb < 2; ++kb)
#pragma unroll
      for (int dk = 0; dk < 4; ++dk) {
        frag8 kf = *(const frag8*)(ksb + koff[kb * 4 + dk]);
        z[kb].v = mfma32(kf, qf[dk], z[kb].v);
      }
    __builtin_amdgcn_s_setprio(0);

    // row max: max3 tree over 32 values, then one permlane32_swap
    float tm;
    {
      const facc16& a = z[0].v; const facc16& c = z[1].v;
      float g0 = vmax3(a[0], a[1], a[2]);
      float g1 = vmax3(a[3], a[4], a[5]);
      float g2 = vmax3(a[6], a[7], a[8]);
      float g3 = vmax3(a[9], a[10], a[11]);
      float g4 = vmax3(a[12], a[13], a[14]);
      float g5 = vmax3(a[15], c[0], c[1]);
      float g6 = vmax3(c[2], c[3], c[4]);
      float g7 = vmax3(c[5], c[6], c[7]);
      float g8 = vmax3(c[8], c[9], c[10]);
      float g9 = vmax3(c[11], c[12], c[13]);
      float h0 = vmax3(g0, g1, g2);
      float h1 = vmax3(g3, g4, g5);
      float h2 = vmax3(g6, g7, g8);
      float h3 = vmax3(g9, c[14], c[15]);
      float t0 = vmax3(h0, h1, h2);
      tm = fmaxf(t0, h3);
      v2i r = pl32swap(__float_as_int(tm), __float_as_int(tm));
      tm = fmaxf(__int_as_float(r.x), __int_as_float(r.y));
    }
    // deferred rescale (cold path)
    if (__any(tm > mrun + 8.f)) {
      float nm = fmaxf(mrun, tm);
      float sc = exp2f((mrun - nm) * L2E);
      mrun = nm; lrun *= sc;
#pragma unroll
      for (int rg = 0; rg < 16; ++rg) {
        int q_r = (rg & 3) + 8 * (rg >> 2) + 4 * hh;
        float scq = __int_as_float(__builtin_amdgcn_ds_bpermute(q_r << 2, __float_as_int(sc)));
        oacc[0][rg] *= scq; oacc[1][rg] *= scq;
      }
    }
    // exp + row-sum + pack (cvt_pk)
    const float mL = mrun * L2E;
    float ps0 = 0.f, ps1 = 0.f, ps2 = 0.f, ps3 = 0.f;
    u32 u[2][4][2];
#pragma unroll
    for (int kb = 0; kb < 2; ++kb)
#pragma unroll
      for (int rg2 = 0; rg2 < 4; ++rg2) {
        float pp0 = exp2f(__builtin_fmaf(z[kb].v[rg2 * 4 + 0], L2E, -mL));
        float pp1 = exp2f(__builtin_fmaf(z[kb].v[rg2 * 4 + 1], L2E, -mL));
        float pp2 = exp2f(__builtin_fmaf(z[kb].v[rg2 * 4 + 2], L2E, -mL));
        float pp3 = exp2f(__builtin_fmaf(z[kb].v[rg2 * 4 + 3], L2E, -mL));
        ps0 += pp0; ps1 += pp1; ps2 += pp2; ps3 += pp3;
        u[kb][rg2][0] = cvtpk(pp0, pp1);
        u[kb][rg2][1] = cvtpk(pp2, pp3);
      }
    float ps = (ps0 + ps1) + (ps2 + ps3);
    {
      v2i r = pl32swap(__float_as_int(ps), __float_as_int(ps));
      ps = __int_as_float(r.x) + __int_as_float(r.y);
    }
    lrun += ps;
    // PV: redistribute P via permlane32_swap into A-frags, mfma against Vs
    const char* vsb = (const char*)&Vs[0][0] + cur * 8192;
    __builtin_amdgcn_s_setprio(1);
#pragma unroll
    for (int km = 0; km < 4; ++km) {
      const int kb = km >> 1, j = km & 1;
      v2i s0 = pl32swap(u[kb][2 * j][0], u[kb][2 * j + 1][0]);
      v2i s1 = pl32swap(u[kb][2 * j][1], u[kb][2 * j + 1][1]);
      i4 pw = { s0.x, s1.x, s0.y, s1.y };
      frag8 pf = *(frag8*)&pw;
#pragma unroll
      for (int nd = 0; nd < 2; ++nd) {
        frag8 vf = *(const frag8*)(vsb + voff[km * 2 + nd]);
        oacc[nd] = mfma32(pf, vf, oacc[nd]);
      }
    }
    __builtin_amdgcn_s_setprio(0);
    asm volatile("s_waitcnt lgkmcnt(0)" ::: "memory");
    __builtin_amdgcn_s_barrier();             // B: all waves done reading buf[cur]
  }
  // epilogue: normalize + store [B,S,E] bf16
  float linv = 1.0f / lrun;
#pragma unroll
  for (int rg = 0; rg < 16; ++rg) {
    int q_r = (rg & 3) + 8 * (rg >> 2) + 4 * hh;
    float lq = __int_as_float(__builtin_amdgcn_ds_bpermute(q_r << 2, __float_as_int(linv)));
    int gq = qt * 128 + w * 32 + q_r;
    size_t rowoff = (size_t)(b * 2048 + gq) * 1024 + hd * 64;
#pragma unroll
    for (int nd = 0; nd < 2; ++nd)
      ao_out[rowoff + nd * 32 + l31] = f2bf_hw(oacc[nd][rg] * lq);
  }
}

// ---------------- out proj GEMM: [4096,1024]x[1024,1024]^T + bias -> fp32 ----------------
__global__ __launch_bounds__(256) void k_gemm_out(
    const u16* __restrict__ A, const u16* __restrict__ B,
    const float* __restrict__ bias, float* __restrict__ out) {
  __shared__ __align__(16) u16 As[128 * 64];
  __shared__ __align__(16) u16 Bs[128 * 64];
  const int mbase = blockIdx.y * 128;
  const int nbase = blockIdx.x * 128;
  const int t = threadIdx.x;
  const int lane = t & 63;
  const int w = t >> 6;
  const int wm = w >> 1, wn = w & 1;
  const facc4 vzero = {0.f, 0.f, 0.f, 0.f};
  facc4 acc[4][4];
#pragma unroll
  for (int i = 0; i < 4; ++i)
#pragma unroll
    for (int j = 0; j < 4; ++j) acc[i][j] = vzero;

  for (int kt = 0; kt < 16; ++kt) {
    __syncthreads();
#pragma unroll
    for (int i = 0; i < 4; ++i) {
      int c = i * 256 + t;
      int row = c >> 3, cs = c & 7;
      int scs = cs ^ (row & 7);
      gload16(A + (size_t)(mbase + row) * 1024 + kt * 64 + scs * 8,
              As + (size_t)(i * 256 + w * 64) * 8);
      gload16(B + (size_t)(nbase + row) * 1024 + kt * 64 + scs * 8,
              Bs + (size_t)(i * 256 + w * 64) * 8);
    }
    __syncthreads();
#pragma unroll
    for (int ks = 0; ks < 2; ++ks) {
      frag8 af[4], bfr[4];
#pragma unroll
      for (int mi = 0; mi < 4; ++mi) {
        int row = wm * 64 + mi * 16 + (lane & 15);
        int off = (ks * 64 + ((lane >> 4) << 4)) ^ ((row & 7) << 4);
        af[mi] = *(const frag8*)((const char*)As + row * 128 + off);
      }
#pragma unroll
      for (int ni = 0; ni < 4; ++ni) {
        int row = wn * 64 + ni * 16 + (lane & 15);
        int off = (ks * 64 + ((lane >> 4) << 4)) ^ ((row & 7) << 4);
        bfr[ni] = *(const frag8*)((const char*)Bs + row * 128 + off);
      }
#pragma unroll
      for (int mi = 0; mi < 4; ++mi)
#pragma unroll
        for (int ni = 0; ni < 4; ++ni)
          acc[mi][ni] = mfma16(af[mi], bfr[ni], acc[mi][ni]);
    }
  }
  const int r0 = (lane >> 4) << 2;
#pragma unroll
  for (int ni = 0; ni < 4; ++ni) {
    const int gc = nbase + wn * 64 + ni * 16 + (lane & 15);
    const float bi = bias[gc];
#pragma unroll
    for (int mi = 0; mi < 4; ++mi)
#pragma unroll
      for (int r = 0; r < 4; ++r) {
        const int gr = mbase + wm * 64 + mi * 16 + r0 + r;
        out[(size_t)gr * 1024 + gc] = acc[mi][ni][r] + bi;
      }
  }
}

extern "C" void kernel_launch(void* const* d_in, const int* in_sizes, int n_in,
                              void* d_out, int out_size, void* d_ws, size_t ws_size,
                              hipStream_t stream) {
  const float* x    = (const float*)d_in[0];
  const float* mask = (const float*)d_in[1];
  const float* wi   = (const float*)d_in[2];
  const float* bi   = (const float*)d_in[3];
  const float* wo   = (const float*)d_in[4];
  const float* bo   = (const float*)d_in[5];
  const float* la   = (const float*)d_in[6];
  const float* lb   = (const float*)d_in[7];
  float* out = (float*)d_out;

  char* ws = (char*)d_ws;
  u16* x_bf  = (u16*)ws;              ws += (size_t)4096 * 1024 * 2;
  u16* w_bf  = (u16*)ws;              ws += (size_t)3072 * 1024 * 2;
  u16* wo_bf = (u16*)ws;              ws += (size_t)1024 * 1024 * 2;
  u16* q_ws  = (u16*)ws;              ws += (size_t)4096 * 1024 * 2;
  u16* k_ws  = (u16*)ws;              ws += (size_t)4096 * 1024 * 2;
  u16* v_pre = (u16*)ws;              ws += (size_t)4096 * 1024 * 2;
  u16* v_t   = (u16*)ws;              ws += (size_t)4096 * 1024 * 2;
  u16* a_ws  = (u16*)ws;              ws += (size_t)4096 * 1024 * 2;
  float* xa  = (float*)ws;            ws += (size_t)4096 * 8 * 4;

  k_cvt<<<dim3(2048), dim3(256), 0, stream>>>(x, x_bf, 4096 * 1024);
  k_cvt<<<dim3(1536), dim3(256), 0, stream>>>(wi, w_bf, 3072 * 1024);
  k_cvt<<<dim3(512),  dim3(256), 0, stream>>>(wo, wo_bf, 1024 * 1024);
  k_xa<<<dim3(1024), dim3(256), 0, stream>>>(x, la, xa);
  k_gemm_qkv<<<dim3(24, 32), dim3(256), 0, stream>>>(x_bf, w_bf, bi, xa, lb,
                                                     q_ws, k_ws, v_pre);
  k_vt<<<dim3(32, 32), dim3(256), 0, stream>>>(v_pre, v_t);
  k_attn<<<dim3(16, 32), dim3(256), 0, stream>>>(q_ws, k_ws, v_t, mask, a_ws);
  k_gemm_out<<<dim3(8, 32), dim3(256), 0, stream>>>(a_ws, wo_bf, bo, out);
}